// Round 1
// baseline (182.888 us; speedup 1.0000x reference)
//
#include <hip/hip_runtime.h>
#include <hip/hip_bf16.h>

#define N_NODES 10000
#define N_EDGES 640000
#define CH 128
#define KN 118   // node_feat inner dim

// K1: fold weights. M[mat][i][c] = sum_j Wn[i][j] * Wa1[mat*128 + j][c]
//     V[mat][c]    = sum_j bn[j]  * Wa1[mat*128 + j][c]  (+ ba1[c] for mat==1)
__global__ __launch_bounds__(128) void k1_weights(
    const float* __restrict__ Wn, const float* __restrict__ bn,
    const float* __restrict__ Wa1, const float* __restrict__ ba1,
    float* __restrict__ M, float* __restrict__ V) {
  int c = threadIdx.x;                 // 0..127
  int mat = blockIdx.x / 119;          // 0: src-half, 1: dst-half
  int i = blockIdx.x % 119;            // 0..117 weight rows, 118 = bias row
  const float* B = Wa1 + mat * CH * CH;
  const float* a = (i < KN) ? (Wn + i * CH) : bn;
  float acc = 0.f;
#pragma unroll 8
  for (int j = 0; j < CH; ++j) acc = fmaf(a[j], B[j * CH + c], acc);
  if (i < KN) {
    M[(mat * KN + i) * CH + c] = acc;
  } else {
    if (mat == 1) acc += ba1[c];
    V[mat * CH + c] = acc;
  }
}

// K2: per-node tables T[mat][n][c] = bf16( nf[n][:] . M[mat][:][c] + V[mat][c] )
// block = 256 threads: c = tx&127, mat = tx>>7; 4 nodes per block.
// nf row accesses are block-uniform -> scalar loads; M loads coalesced.
__global__ __launch_bounds__(256) void k2_nodes(
    const float* __restrict__ nf, const float* __restrict__ M,
    const float* __restrict__ V, __hip_bfloat16* __restrict__ T) {
  int tx = threadIdx.x;
  int c = tx & (CH - 1);
  int mat = tx >> 7;
  int n0 = blockIdx.x * 4;
  const float* Mm = M + mat * KN * CH + c;
  const float* r0 = nf + (size_t)(n0 + 0) * KN;
  const float* r1 = nf + (size_t)(n0 + 1) * KN;
  const float* r2 = nf + (size_t)(n0 + 2) * KN;
  const float* r3 = nf + (size_t)(n0 + 3) * KN;
  float a0 = 0.f, a1 = 0.f, a2 = 0.f, a3 = 0.f;
#pragma unroll 2
  for (int k = 0; k < KN; ++k) {
    float m = Mm[k * CH];
    a0 = fmaf(r0[k], m, a0);
    a1 = fmaf(r1[k], m, a1);
    a2 = fmaf(r2[k], m, a2);
    a3 = fmaf(r3[k], m, a3);
  }
  float v = V[mat * CH + c];
  __hip_bfloat16* t = T + (size_t)mat * N_NODES * CH + c;
  t[(size_t)(n0 + 0) * CH] = __float2bfloat16(a0 + v);
  t[(size_t)(n0 + 1) * CH] = __float2bfloat16(a1 + v);
  t[(size_t)(n0 + 2) * CH] = __float2bfloat16(a2 + v);
  t[(size_t)(n0 + 3) * CH] = __float2bfloat16(a3 + v);
}

// K3: per edge e: out[e] = b2 + sum_c w2[c] * lrelu(S[src[e]][c] + D[dst[e]][c])
// 16 lanes per edge, 8 channels per lane (one 16B bf16x8 load per table).
__global__ __launch_bounds__(256) void k3_edges(
    const int* __restrict__ src, const int* __restrict__ dst,
    const __hip_bfloat16* __restrict__ S, const __hip_bfloat16* __restrict__ D,
    const float* __restrict__ w2, const float* __restrict__ b2,
    float* __restrict__ out) {
  int tid = blockIdx.x * 256 + threadIdx.x;
  int eid = tid >> 4;
  int sub = tid & 15;
  int c0 = sub << 3;            // 8 channels per lane
  float w[8];
#pragma unroll
  for (int i = 0; i < 8; ++i) w[i] = w2[c0 + i];
  int s = src[eid];
  int d = dst[eid];
  const uint4* sp = (const uint4*)(S + (size_t)s * CH + c0);
  const uint4* dp = (const uint4*)(D + (size_t)d * CH + c0);
  uint4 su = *sp;
  uint4 du = *dp;
  unsigned us[4] = {su.x, su.y, su.z, su.w};
  unsigned ud[4] = {du.x, du.y, du.z, du.w};
  float acc = 0.f;
#pragma unroll
  for (int i = 0; i < 4; ++i) {
    float s0 = __uint_as_float(us[i] << 16);
    float s1 = __uint_as_float(us[i] & 0xffff0000u);
    float d0 = __uint_as_float(ud[i] << 16);
    float d1 = __uint_as_float(ud[i] & 0xffff0000u);
    float t0 = s0 + d0;
    float t1 = s1 + d1;
    float u0 = fmaxf(t0, 0.01f * t0);   // leaky_relu, slope 0.01
    float u1 = fmaxf(t1, 0.01f * t1);
    acc = fmaf(u0, w[2 * i], acc);
    acc = fmaf(u1, w[2 * i + 1], acc);
  }
  // reduce across the 16-lane group (xor masks stay within the group)
  acc += __shfl_xor(acc, 1);
  acc += __shfl_xor(acc, 2);
  acc += __shfl_xor(acc, 4);
  acc += __shfl_xor(acc, 8);
  if (sub == 0) out[eid] = acc + b2[0];
}

extern "C" void kernel_launch(void* const* d_in, const int* in_sizes, int n_in,
                              void* d_out, int out_size, void* d_ws, size_t ws_size,
                              hipStream_t stream) {
  const float* nf  = (const float*)d_in[0];
  // d_in[1] edge_feat, d_in[6] W_edge, d_in[7] b_edge: unused by the output
  const int*   src = (const int*)d_in[2];
  const int*   dst = (const int*)d_in[3];
  const float* Wn  = (const float*)d_in[4];
  const float* bn  = (const float*)d_in[5];
  const float* Wa1 = (const float*)d_in[8];
  const float* ba1 = (const float*)d_in[9];
  const float* Wa2 = (const float*)d_in[10];
  const float* ba2 = (const float*)d_in[11];
  float* out = (float*)d_out;

  char* ws = (char*)d_ws;
  float* M = (float*)ws;                                   // [2][118][128] f32
  float* V = (float*)(ws + 2 * KN * CH * sizeof(float));   // [2][128] f32
  __hip_bfloat16* T =
      (__hip_bfloat16*)(ws + 2 * KN * CH * sizeof(float) + 2 * CH * sizeof(float));
  __hip_bfloat16* S = T;                                   // [10000][128] bf16
  __hip_bfloat16* D = T + (size_t)N_NODES * CH;            // [10000][128] bf16

  k1_weights<<<238, 128, 0, stream>>>(Wn, bn, Wa1, ba1, M, V);
  k2_nodes<<<N_NODES / 4, 256, 0, stream>>>(nf, M, V, T);
  k3_edges<<<(N_EDGES * 16) / 256, 256, 0, stream>>>(src, dst, S, D, Wa2, ba2, out);
}

// Round 2
// 170.215 us; speedup vs baseline: 1.0745x; 1.0745x over previous
//
#include <hip/hip_runtime.h>
#include <hip/hip_bf16.h>

#define N_NODES 10000
#define N_EDGES 640000
#define CH 128
#define KN 118   // node_feat inner dim

typedef float v2f __attribute__((ext_vector_type(2)));

// K1: fold weights. M[mat][i][c] = sum_j Wn[i][j] * Wa1[mat*128 + j][c]
//     V[mat][c]    = sum_j bn[j]  * Wa1[mat*128 + j][c]  (+ ba1[c] for mat==1)
__global__ __launch_bounds__(128) void k1_weights(
    const float* __restrict__ Wn, const float* __restrict__ bn,
    const float* __restrict__ Wa1, const float* __restrict__ ba1,
    float* __restrict__ M, float* __restrict__ V) {
  int c = threadIdx.x;                 // 0..127
  int mat = blockIdx.x / 119;          // 0: src-half, 1: dst-half
  int i = blockIdx.x % 119;            // 0..117 weight rows, 118 = bias row
  const float* B = Wa1 + mat * CH * CH;
  const float* a = (i < KN) ? (Wn + i * CH) : bn;
  float acc = 0.f;
#pragma unroll 8
  for (int j = 0; j < CH; ++j) acc = fmaf(a[j], B[j * CH + c], acc);
  if (i < KN) {
    M[(mat * KN + i) * CH + c] = acc;
  } else {
    if (mat == 1) acc += ba1[c];
    V[mat * CH + c] = acc;
  }
}

// K2: per-node tables T[mat][n][c] = bf16( nf[n][:] . M[mat][:][c] + V[mat][c] )
// block = 256: c = tx&127, mat = tx>>7; 8 nodes per block (halves M re-reads
// vs 4/block). nf loads are block-uniform -> scalar unit; M loads coalesced.
__global__ __launch_bounds__(256) void k2_nodes(
    const float* __restrict__ nf, const float* __restrict__ M,
    const float* __restrict__ V, __hip_bfloat16* __restrict__ T) {
  int tx = threadIdx.x;
  int c = tx & (CH - 1);
  int mat = tx >> 7;
  int n0 = blockIdx.x * 8;
  const float* Mm = M + mat * KN * CH + c;
  const float* r = nf + (size_t)n0 * KN;
  float acc[8];
#pragma unroll
  for (int j = 0; j < 8; ++j) acc[j] = 0.f;
#pragma unroll 2
  for (int k = 0; k < KN; ++k) {
    float m = Mm[k * CH];
#pragma unroll
    for (int j = 0; j < 8; ++j) acc[j] = fmaf(r[j * KN + k], m, acc[j]);
  }
  float v = V[mat * CH + c];
  __hip_bfloat16* t = T + (size_t)mat * N_NODES * CH + c;
#pragma unroll
  for (int j = 0; j < 8; ++j)
    t[(size_t)(n0 + j) * CH] = __float2bfloat16(acc[j] + v);
}

__device__ inline v2f unpack2(unsigned u) {
  v2f r;
  r.x = __uint_as_float(u << 16);
  r.y = __uint_as_float(u & 0xffff0000u);
  return r;
}

// K3: out[e] = b2 + sum_c w2[c] * lrelu(S[src[e]][c] + D[dst[e]][c])
// 16 lanes per edge-PAIR slot, 8 channels per lane, 2 edges per thread.
// Packed-f32 (v_pk_*) channel math; float4 w2 loads; int2 idx; float2 store.
__global__ __launch_bounds__(256) void k3_edges(
    const int* __restrict__ src, const int* __restrict__ dst,
    const __hip_bfloat16* __restrict__ S, const __hip_bfloat16* __restrict__ D,
    const float* __restrict__ w2, const float* __restrict__ b2,
    float* __restrict__ out) {
  int tid = blockIdx.x * 256 + threadIdx.x;
  int g = tid >> 4;             // edge-pair id, 0..N_EDGES/2-1
  int sub = tid & 15;
  int c0 = sub << 3;            // 8 channels per lane

  v2f w[4];
  {
    float4 w0 = *(const float4*)(w2 + c0);
    float4 w1 = *(const float4*)(w2 + c0 + 4);
    w[0] = v2f{w0.x, w0.y};
    w[1] = v2f{w0.z, w0.w};
    w[2] = v2f{w1.x, w1.y};
    w[3] = v2f{w1.z, w1.w};
  }
  int2 sp = *(const int2*)(src + 2 * g);
  int2 dp = *(const int2*)(dst + 2 * g);
  uint4 sA = *(const uint4*)(S + (size_t)sp.x * CH + c0);
  uint4 dA = *(const uint4*)(D + (size_t)dp.x * CH + c0);
  uint4 sB = *(const uint4*)(S + (size_t)sp.y * CH + c0);
  uint4 dB = *(const uint4*)(D + (size_t)dp.y * CH + c0);

  unsigned usA[4] = {sA.x, sA.y, sA.z, sA.w};
  unsigned udA[4] = {dA.x, dA.y, dA.z, dA.w};
  unsigned usB[4] = {sB.x, sB.y, sB.z, sB.w};
  unsigned udB[4] = {dB.x, dB.y, dB.z, dB.w};

  v2f accA = v2f{0.f, 0.f};
  v2f accB = v2f{0.f, 0.f};
#pragma unroll
  for (int i = 0; i < 4; ++i) {
    v2f tA = unpack2(usA[i]) + unpack2(udA[i]);
    v2f tB = unpack2(usB[i]) + unpack2(udB[i]);
    v2f pA = tA * 0.01f;      // v_pk_mul_f32
    v2f pB = tB * 0.01f;
    v2f uA = v2f{fmaxf(tA.x, pA.x), fmaxf(tA.y, pA.y)};  // v_pk_max_f32
    v2f uB = v2f{fmaxf(tB.x, pB.x), fmaxf(tB.y, pB.y)};
    accA += uA * w[i];        // v_pk_fma_f32 (ffp-contract=fast)
    accB += uB * w[i];
  }
  float a = accA.x + accA.y;
  float b = accB.x + accB.y;
  // reduce across the 16-lane group (xor masks stay within the group)
#pragma unroll
  for (int m = 1; m < 16; m <<= 1) {
    a += __shfl_xor(a, m);
    b += __shfl_xor(b, m);
  }
  if (sub == 0) {
    float bias = b2[0];
    *(float2*)(out + 2 * g) = float2{a + bias, b + bias};
  }
}

extern "C" void kernel_launch(void* const* d_in, const int* in_sizes, int n_in,
                              void* d_out, int out_size, void* d_ws, size_t ws_size,
                              hipStream_t stream) {
  const float* nf  = (const float*)d_in[0];
  // d_in[1] edge_feat, d_in[6] W_edge, d_in[7] b_edge: unused by the output
  const int*   src = (const int*)d_in[2];
  const int*   dst = (const int*)d_in[3];
  const float* Wn  = (const float*)d_in[4];
  const float* bn  = (const float*)d_in[5];
  const float* Wa1 = (const float*)d_in[8];
  const float* ba1 = (const float*)d_in[9];
  const float* Wa2 = (const float*)d_in[10];
  const float* ba2 = (const float*)d_in[11];
  float* out = (float*)d_out;

  char* ws = (char*)d_ws;
  float* M = (float*)ws;                                   // [2][118][128] f32
  float* V = (float*)(ws + 2 * KN * CH * sizeof(float));   // [2][128] f32
  __hip_bfloat16* T =
      (__hip_bfloat16*)(ws + 2 * KN * CH * sizeof(float) + 2 * CH * sizeof(float));
  __hip_bfloat16* S = T;                                   // [10000][128] bf16
  __hip_bfloat16* D = T + (size_t)N_NODES * CH;            // [10000][128] bf16

  k1_weights<<<238, 128, 0, stream>>>(Wn, bn, Wa1, ba1, M, V);
  k2_nodes<<<N_NODES / 8, 256, 0, stream>>>(nf, M, V, T);
  k3_edges<<<(N_EDGES / 2 * 16) / 256, 256, 0, stream>>>(src, dst, S, D, Wa2, ba2, out);
}

// Round 3
// 167.349 us; speedup vs baseline: 1.0929x; 1.0171x over previous
//
#include <hip/hip_runtime.h>
#include <hip/hip_bf16.h>

#define N_NODES 10000
#define N_EDGES 640000
#define CH 128
#define KN 118   // node_feat inner dim

typedef _Float16 h2 __attribute__((ext_vector_type(2)));
typedef _Float16 h8 __attribute__((ext_vector_type(8)));

#define H2_OF(v, k) __builtin_shufflevector((v), (v), 2 * (k), 2 * (k) + 1)

// K1: fold weights. M[mat][i][c] = sum_j Wn[i][j] * Wa1[mat*128 + j][c]
//     V[mat][c]    = sum_j bn[j]  * Wa1[mat*128 + j][c]  (+ ba1[c] for mat==1)
// Extra block (mat==2): convert w2 -> f16 table for k3.
__global__ __launch_bounds__(128) void k1_weights(
    const float* __restrict__ Wn, const float* __restrict__ bn,
    const float* __restrict__ Wa1, const float* __restrict__ ba1,
    const float* __restrict__ w2, float* __restrict__ M,
    float* __restrict__ V, _Float16* __restrict__ w2h) {
  int c = threadIdx.x;                 // 0..127
  int mat = blockIdx.x / 119;          // 0: src-half, 1: dst-half, 2: w2 conv
  int i = blockIdx.x % 119;            // 0..117 weight rows, 118 = bias row
  if (mat == 2) {
    w2h[c] = (_Float16)w2[c];
    return;
  }
  const float* B = Wa1 + mat * CH * CH;
  const float* a = (i < KN) ? (Wn + i * CH) : bn;
  float acc = 0.f;
#pragma unroll 8
  for (int j = 0; j < CH; ++j) acc = fmaf(a[j], B[j * CH + c], acc);
  if (i < KN) {
    M[(mat * KN + i) * CH + c] = acc;
  } else {
    if (mat == 1) acc += ba1[c];
    V[mat * CH + c] = acc;
  }
}

// K2: per-node tables T[mat][n][c] = f16( nf[n][:] . M[mat][:][c] + V[mat][c] )
// block = 256: c = tx&127, mat = tx>>7; 8 nodes per block. nf loads are
// block-uniform -> scalar unit; M loads coalesced.
__global__ __launch_bounds__(256) void k2_nodes(
    const float* __restrict__ nf, const float* __restrict__ M,
    const float* __restrict__ V, _Float16* __restrict__ T) {
  int tx = threadIdx.x;
  int c = tx & (CH - 1);
  int mat = tx >> 7;
  int n0 = blockIdx.x * 8;
  const float* Mm = M + mat * KN * CH + c;
  const float* r = nf + (size_t)n0 * KN;
  float acc[8];
#pragma unroll
  for (int j = 0; j < 8; ++j) acc[j] = 0.f;
#pragma unroll 2
  for (int k = 0; k < KN; ++k) {
    float m = Mm[k * CH];
#pragma unroll
    for (int j = 0; j < 8; ++j) acc[j] = fmaf(r[j * KN + k], m, acc[j]);
  }
  float v = V[mat * CH + c];
  _Float16* t = T + (size_t)mat * N_NODES * CH + c;
#pragma unroll
  for (int j = 0; j < 8; ++j)
    t[(size_t)(n0 + j) * CH] = (_Float16)(acc[j] + v);
}

// lrelu(s+d) . w over 8 channels, f32 accumulate via v_dot2_f32_f16
__device__ inline float edge_acc8(h8 s, h8 d, h8 w, float acc) {
  h8 t = s + d;                                  // 4x v_pk_add_f16
  h8 p = t * (_Float16)0.01f;                    // 4x v_pk_mul_f16
  h8 u = __builtin_elementwise_max(t, p);        // 4x v_pk_max_f16 (leaky relu)
  acc = __builtin_amdgcn_fdot2(H2_OF(u, 0), H2_OF(w, 0), acc, false);
  acc = __builtin_amdgcn_fdot2(H2_OF(u, 1), H2_OF(w, 1), acc, false);
  acc = __builtin_amdgcn_fdot2(H2_OF(u, 2), H2_OF(w, 2), acc, false);
  acc = __builtin_amdgcn_fdot2(H2_OF(u, 3), H2_OF(w, 3), acc, false);
  return acc;
}

// K3: out[e] = b2 + sum_c w2[c] * lrelu(S[src[e]][c] + D[dst[e]][c])
// 16 lanes per edge-pair slot, 8 channels per lane, 2 edges per thread.
__global__ __launch_bounds__(256) void k3_edges(
    const int* __restrict__ src, const int* __restrict__ dst,
    const _Float16* __restrict__ S, const _Float16* __restrict__ D,
    const _Float16* __restrict__ w2h, const float* __restrict__ b2,
    float* __restrict__ out) {
  int tid = blockIdx.x * 256 + threadIdx.x;
  int g = tid >> 4;             // edge-pair id, 0..N_EDGES/2-1
  int sub = tid & 15;
  int c0 = sub << 3;            // 8 channels per lane

  h8 w = *(const h8*)(w2h + c0);
  int2 sp = *(const int2*)(src + 2 * g);
  int2 dp = *(const int2*)(dst + 2 * g);
  h8 sA = *(const h8*)(S + (size_t)sp.x * CH + c0);
  h8 dA = *(const h8*)(D + (size_t)dp.x * CH + c0);
  h8 sB = *(const h8*)(S + (size_t)sp.y * CH + c0);
  h8 dB = *(const h8*)(D + (size_t)dp.y * CH + c0);

  float a = edge_acc8(sA, dA, w, 0.f);
  float b = edge_acc8(sB, dB, w, 0.f);

  // reduce across the 16-lane group (xor masks stay within the group)
#pragma unroll
  for (int m = 1; m < 16; m <<= 1) {
    a += __shfl_xor(a, m);
    b += __shfl_xor(b, m);
  }
  if (sub == 0) {
    float bias = b2[0];
    *(float2*)(out + 2 * g) = float2{a + bias, b + bias};
  }
}

extern "C" void kernel_launch(void* const* d_in, const int* in_sizes, int n_in,
                              void* d_out, int out_size, void* d_ws, size_t ws_size,
                              hipStream_t stream) {
  const float* nf  = (const float*)d_in[0];
  // d_in[1] edge_feat, d_in[6] W_edge, d_in[7] b_edge: unused by the output
  const int*   src = (const int*)d_in[2];
  const int*   dst = (const int*)d_in[3];
  const float* Wn  = (const float*)d_in[4];
  const float* bn  = (const float*)d_in[5];
  const float* Wa1 = (const float*)d_in[8];
  const float* ba1 = (const float*)d_in[9];
  const float* Wa2 = (const float*)d_in[10];
  const float* ba2 = (const float*)d_in[11];
  float* out = (float*)d_out;

  char* ws = (char*)d_ws;
  float* M = (float*)ws;                                   // [2][118][128] f32
  float* V = (float*)(ws + 2 * KN * CH * sizeof(float));   // [2][128] f32
  _Float16* w2h = (_Float16*)(ws + (2 * KN * CH + 2 * CH) * sizeof(float));
  _Float16* T = (_Float16*)((char*)w2h + CH * sizeof(_Float16));
  _Float16* S = T;                                         // [10000][128] f16
  _Float16* D = T + (size_t)N_NODES * CH;                  // [10000][128] f16

  k1_weights<<<239, 128, 0, stream>>>(Wn, bn, Wa1, ba1, Wa2, M, V, w2h);
  k2_nodes<<<N_NODES / 8, 256, 0, stream>>>(nf, M, V, T);
  k3_edges<<<(N_EDGES / 2 * 16) / 256, 256, 0, stream>>>(src, dst, S, D, w2h, ba2, out);
}

// Round 4
// 163.847 us; speedup vs baseline: 1.1162x; 1.0214x over previous
//
#include <hip/hip_runtime.h>
#include <hip/hip_bf16.h>

#define N_NODES 10000
#define N_EDGES 640000
#define CH 128
#define KN 118   // node_feat inner dim

typedef _Float16 h2 __attribute__((ext_vector_type(2)));
typedef _Float16 h8 __attribute__((ext_vector_type(8)));

#define H2_OF(v, k) __builtin_shufflevector((v), (v), 2 * (k), 2 * (k) + 1)

// K1: fold weights. M[mat][i][c] = sum_j Wn[i][j] * Wa1[mat*128 + j][c]
//     V[mat][c]    = sum_j bn[j]  * Wa1[mat*128 + j][c]  (+ ba1[c] for mat==1)
// Extra block (mat==2): convert w2 -> f16 table for k3.
__global__ __launch_bounds__(128) void k1_weights(
    const float* __restrict__ Wn, const float* __restrict__ bn,
    const float* __restrict__ Wa1, const float* __restrict__ ba1,
    const float* __restrict__ w2, float* __restrict__ M,
    float* __restrict__ V, _Float16* __restrict__ w2h) {
  int c = threadIdx.x;                 // 0..127
  int mat = blockIdx.x / 119;          // 0: src-half, 1: dst-half, 2: w2 conv
  int i = blockIdx.x % 119;            // 0..117 weight rows, 118 = bias row
  if (mat == 2) {
    w2h[c] = (_Float16)w2[c];
    return;
  }
  const float* B = Wa1 + mat * CH * CH;
  const float* a = (i < KN) ? (Wn + i * CH) : bn;
  float acc = 0.f;
#pragma unroll 8
  for (int j = 0; j < CH; ++j) acc = fmaf(a[j], B[j * CH + c], acc);
  if (i < KN) {
    M[(mat * KN + i) * CH + c] = acc;
  } else {
    if (mat == 1) acc += ba1[c];
    V[mat * CH + c] = acc;
  }
}

// K2: per-node tables T[mat][n][c] = f16( nf[n][:] . M[mat][:][c] + V[mat][c] )
// block = 256: c = tx&127, mat = tx>>7; 8 nodes per block. nf loads are
// block-uniform -> scalar unit; M loads coalesced.
__global__ __launch_bounds__(256) void k2_nodes(
    const float* __restrict__ nf, const float* __restrict__ M,
    const float* __restrict__ V, _Float16* __restrict__ T) {
  int tx = threadIdx.x;
  int c = tx & (CH - 1);
  int mat = tx >> 7;
  int n0 = blockIdx.x * 8;
  const float* Mm = M + mat * KN * CH + c;
  const float* r = nf + (size_t)n0 * KN;
  float acc[8];
#pragma unroll
  for (int j = 0; j < 8; ++j) acc[j] = 0.f;
#pragma unroll 2
  for (int k = 0; k < KN; ++k) {
    float m = Mm[k * CH];
#pragma unroll
    for (int j = 0; j < 8; ++j) acc[j] = fmaf(r[j * KN + k], m, acc[j]);
  }
  float v = V[mat * CH + c];
  _Float16* t = T + (size_t)mat * N_NODES * CH + c;
#pragma unroll
  for (int j = 0; j < 8; ++j)
    t[(size_t)(n0 + j) * CH] = (_Float16)(acc[j] + v);
}

// lrelu(s+d) . w over 8 channels, f32 accumulate via v_dot2_f32_f16
__device__ inline float edge_acc8(h8 s, h8 d, h8 w) {
  h8 t = s + d;                                  // 4x v_pk_add_f16
  h8 p = t * (_Float16)0.01f;                    // 4x v_pk_mul_f16
  h8 u = __builtin_elementwise_max(t, p);        // 4x v_pk_max_f16 (leaky relu)
  float acc = 0.f;
  acc = __builtin_amdgcn_fdot2(H2_OF(u, 0), H2_OF(w, 0), acc, false);
  acc = __builtin_amdgcn_fdot2(H2_OF(u, 1), H2_OF(w, 1), acc, false);
  acc = __builtin_amdgcn_fdot2(H2_OF(u, 2), H2_OF(w, 2), acc, false);
  acc = __builtin_amdgcn_fdot2(H2_OF(u, 3), H2_OF(w, 3), acc, false);
  return acc;
}

// K3: out[e] = b2 + sum_c w2[c] * lrelu(S[src[e]][c] + D[dst[e]][c])
// 16 lanes per edge-QUAD slot, 8 channels per lane, 4 edges per thread.
// 8 row-gathers in flight per thread; packed-butterfly reduction (8 shfl for
// 4 edges); lanes 0-3 do coalesced scalar stores.
__global__ __launch_bounds__(256) void k3_edges(
    const int* __restrict__ src, const int* __restrict__ dst,
    const _Float16* __restrict__ S, const _Float16* __restrict__ D,
    const _Float16* __restrict__ w2h, const float* __restrict__ b2,
    float* __restrict__ out) {
  int tid = blockIdx.x * 256 + threadIdx.x;
  int g = tid >> 4;             // edge-quad id, 0..N_EDGES/4-1
  int sub = tid & 15;
  int c0 = sub << 3;            // 8 channels per lane

  h8 w = *(const h8*)(w2h + c0);
  int4 s4 = *(const int4*)(src + 4 * g);   // broadcast across the 16 lanes
  int4 d4 = *(const int4*)(dst + 4 * g);

  const _Float16* Sp = S + c0;
  const _Float16* Dp = D + c0;
  h8 sr0 = *(const h8*)(Sp + ((size_t)s4.x << 7));
  h8 dr0 = *(const h8*)(Dp + ((size_t)d4.x << 7));
  h8 sr1 = *(const h8*)(Sp + ((size_t)s4.y << 7));
  h8 dr1 = *(const h8*)(Dp + ((size_t)d4.y << 7));
  h8 sr2 = *(const h8*)(Sp + ((size_t)s4.z << 7));
  h8 dr2 = *(const h8*)(Dp + ((size_t)d4.z << 7));
  h8 sr3 = *(const h8*)(Sp + ((size_t)s4.w << 7));
  h8 dr3 = *(const h8*)(Dp + ((size_t)d4.w << 7));

  float a0 = edge_acc8(sr0, dr0, w);
  float a1 = edge_acc8(sr1, dr1, w);
  float a2 = edge_acc8(sr2, dr2, w);
  float a3 = edge_acc8(sr3, dr3, w);

  // packed butterfly: after this, lane (sub&3)==k holds sum of edge k
  float r0 = a0 + __shfl_xor(a0, 1);
  float r1 = a1 + __shfl_xor(a1, 1);
  float r2 = a2 + __shfl_xor(a2, 1);
  float r3 = a3 + __shfl_xor(a3, 1);
  float v1 = (sub & 1) ? r1 : r0;
  float v2 = (sub & 1) ? r3 : r2;
  float t1 = v1 + __shfl_xor(v1, 2);
  float t2 = v2 + __shfl_xor(v2, 2);
  float u = (sub & 2) ? t2 : t1;
  u += __shfl_xor(u, 4);
  u += __shfl_xor(u, 8);

  if (sub < 4) out[4 * g + sub] = u + b2[0];
}

extern "C" void kernel_launch(void* const* d_in, const int* in_sizes, int n_in,
                              void* d_out, int out_size, void* d_ws, size_t ws_size,
                              hipStream_t stream) {
  const float* nf  = (const float*)d_in[0];
  // d_in[1] edge_feat, d_in[6] W_edge, d_in[7] b_edge: unused by the output
  const int*   src = (const int*)d_in[2];
  const int*   dst = (const int*)d_in[3];
  const float* Wn  = (const float*)d_in[4];
  const float* bn  = (const float*)d_in[5];
  const float* Wa1 = (const float*)d_in[8];
  const float* ba1 = (const float*)d_in[9];
  const float* Wa2 = (const float*)d_in[10];
  const float* ba2 = (const float*)d_in[11];
  float* out = (float*)d_out;

  char* ws = (char*)d_ws;
  float* M = (float*)ws;                                   // [2][118][128] f32
  float* V = (float*)(ws + 2 * KN * CH * sizeof(float));   // [2][128] f32
  _Float16* w2h = (_Float16*)(ws + (2 * KN * CH + 2 * CH) * sizeof(float));
  _Float16* T = (_Float16*)((char*)w2h + CH * sizeof(_Float16));
  _Float16* S = T;                                         // [10000][128] f16
  _Float16* D = T + (size_t)N_NODES * CH;                  // [10000][128] f16

  k1_weights<<<239, 128, 0, stream>>>(Wn, bn, Wa1, ba1, Wa2, M, V, w2h);
  k2_nodes<<<N_NODES / 8, 256, 0, stream>>>(nf, M, V, T);
  k3_edges<<<(N_EDGES / 4 * 16) / 256, 256, 0, stream>>>(src, dst, S, D, w2h, ba2, out);
}